// Round 7
// baseline (635.711 us; speedup 1.0000x reference)
//
#include <hip/hip_runtime.h>
#include <math.h>

// SimpleGNN: out = softplus(A(relu(A(relu(A(x W1)+b1) W2)+b2) Wout)+bout)
// using spmm(x) @ W == spmm(x @ W) to make the last spmm D=1.
// CSR edges stored as packed (col,val) int2 pairs -> single 8B store in scatter.

// ---------------- CSR build ----------------
__global__ void k_hist(const int* __restrict__ row, int* __restrict__ cnt, int E){
  int e = blockIdx.x*256 + threadIdx.x;
  if(e < E) atomicAdd(&cnt[row[e]], 1);
}

// per-tile exclusive scan (tile=1024); writes local-exclusive values + tile totals
__global__ void k_scan1(const int* __restrict__ cnt, int* __restrict__ scanned,
                        int* __restrict__ sums, int n){
  __shared__ int tmp[1024];
  int i = blockIdx.x*1024 + threadIdx.x;
  int v = (i<n)? cnt[i] : 0;
  tmp[threadIdx.x] = v;
  __syncthreads();
  for(int off=1; off<1024; off<<=1){
    int t = (threadIdx.x>=off)? tmp[threadIdx.x-off] : 0;
    __syncthreads();
    tmp[threadIdx.x] += t;
    __syncthreads();
  }
  if(i<n) scanned[i] = tmp[threadIdx.x] - v;      // local exclusive
  if(threadIdx.x==1023) sums[blockIdx.x] = tmp[1023];
}

__global__ void k_scan2(int* sums, int ntiles){
  if(threadIdx.x==0 && blockIdx.x==0){
    int acc=0;
    for(int i=0;i<ntiles;i++){ int v=sums[i]; sums[i]=acc; acc+=v; }
  }
}

__global__ void k_scan3(const int* __restrict__ scanned, const int* __restrict__ sums,
                        int* __restrict__ row_ptr, int* __restrict__ offs, int n, int E){
  int i = blockIdx.x*256 + threadIdx.x;
  if(i<n){ int ex = scanned[i] + sums[i>>10]; row_ptr[i]=ex; offs[i]=ex; }
  else if(i==n){ row_ptr[n]=E; }
}

// packed scatter: one 8B store per edge (col,val in the same cacheline)
__global__ void k_scatter(const int* __restrict__ row, const int* __restrict__ col,
                          const float* __restrict__ val, int* __restrict__ offs,
                          int2* __restrict__ pairs, int E){
  int e = blockIdx.x*256 + threadIdx.x;
  if(e<E){
    int p = atomicAdd(&offs[row[e]],1);
    pairs[p] = make_int2(col[e], __float_as_int(val[e]));
  }
}

// ---------------- dense GEMM: Y[n,128] = X[n,128] @ W[128,128] ----------------
// 128x128 block tile, BK=32, 256 threads, 8x8 per-thread register tile.
__global__ __launch_bounds__(256) void k_gemm(const float* __restrict__ X,
                                              const float* __restrict__ W,
                                              float* __restrict__ Y, int n){
  __shared__ float xs_t[32][128];   // [k][row] transposed x tile
  __shared__ float ws[32][128];     // [k][col]
  const int t   = threadIdx.x;
  const int row0 = blockIdx.x * 128;
  const int cg  = t & 15;           // col group: cols cg*8 .. cg*8+7
  const int rg  = t >> 4;           // row group: rows rg*8 .. rg*8+7

  float acc[8][8];
  #pragma unroll
  for(int i=0;i<8;i++)
    #pragma unroll
    for(int j=0;j<8;j++) acc[i][j]=0.f;

  for(int kt=0; kt<128; kt+=32){
    // stage x transposed: thread -> row r = t>>1, half q = t&1 (16 floats)
    {
      int r = t>>1, q = t&1;
      int gr = row0 + r;
      float4 a = make_float4(0,0,0,0), b = a, c = a, d = a;
      if(gr < n){
        const float4* src = (const float4*)(X + (size_t)gr*128 + kt + q*16);
        a = src[0]; b = src[1]; c = src[2]; d = src[3];
      }
      int kb = q*16;
      xs_t[kb+ 0][r]=a.x; xs_t[kb+ 1][r]=a.y; xs_t[kb+ 2][r]=a.z; xs_t[kb+ 3][r]=a.w;
      xs_t[kb+ 4][r]=b.x; xs_t[kb+ 5][r]=b.y; xs_t[kb+ 6][r]=b.z; xs_t[kb+ 7][r]=b.w;
      xs_t[kb+ 8][r]=c.x; xs_t[kb+ 9][r]=c.y; xs_t[kb+10][r]=c.z; xs_t[kb+11][r]=c.w;
      xs_t[kb+12][r]=d.x; xs_t[kb+13][r]=d.y; xs_t[kb+14][r]=d.z; xs_t[kb+15][r]=d.w;
    }
    // stage W: linear float4 mapping (coalesced, conflict-free)
    #pragma unroll
    for(int rep=0; rep<4; rep++){
      int f  = t + rep*256;        // float4 index in [0,1024)
      int kr = f >> 5;             // 32 float4 per k-row
      int cq = f & 31;
      float4 w = *(const float4*)(W + (size_t)(kt+kr)*128 + cq*4);
      *(float4*)&ws[kr][cq*4] = w;
    }
    __syncthreads();

    #pragma unroll
    for(int kk=0; kk<32; kk++){
      float4 wv0 = *(const float4*)&ws[kk][cg*8];
      float4 wv1 = *(const float4*)&ws[kk][cg*8+4];
      #pragma unroll
      for(int i=0;i<8;i++){
        float xv = xs_t[kk][rg*8+i];
        acc[i][0] = fmaf(xv, wv0.x, acc[i][0]);
        acc[i][1] = fmaf(xv, wv0.y, acc[i][1]);
        acc[i][2] = fmaf(xv, wv0.z, acc[i][2]);
        acc[i][3] = fmaf(xv, wv0.w, acc[i][3]);
        acc[i][4] = fmaf(xv, wv1.x, acc[i][4]);
        acc[i][5] = fmaf(xv, wv1.y, acc[i][5]);
        acc[i][6] = fmaf(xv, wv1.z, acc[i][6]);
        acc[i][7] = fmaf(xv, wv1.w, acc[i][7]);
      }
    }
    __syncthreads();
  }

  #pragma unroll
  for(int i=0;i<8;i++){
    int gr = row0 + rg*8 + i;
    if(gr < n){
      float* dst = Y + (size_t)gr*128 + cg*8;
      *(float4*)dst     = make_float4(acc[i][0],acc[i][1],acc[i][2],acc[i][3]);
      *(float4*)(dst+4) = make_float4(acc[i][4],acc[i][5],acc[i][6],acc[i][7]);
    }
  }
}

// ---------------- SpMM (D=128) + bias + relu: h[r] = relu(sum val*y[col] + b) ----------------
// one wave per row, float2 per lane, 4-wide edge unroll for ILP (4 gathers in flight)
__global__ __launch_bounds__(256) void k_spmm_relu(const int* __restrict__ row_ptr,
                                                   const int2* __restrict__ pairs,
                                                   const float* __restrict__ y,
                                                   const float* __restrict__ bias,
                                                   float* __restrict__ h, int n){
  int wid  = (int)((blockIdx.x*(size_t)blockDim.x + threadIdx.x) >> 6);
  int lane = threadIdx.x & 63;
  if(wid >= n) return;
  int s = row_ptr[wid], e = row_ptr[wid+1];
  float2 a0 = make_float2(0.f,0.f), a1 = a0, a2 = a0, a3 = a0;
  int i = s;
  for(; i+4 <= e; i += 4){
    int2 p0 = pairs[i],   p1 = pairs[i+1], p2 = pairs[i+2], p3 = pairs[i+3];
    float2 x0 = ((const float2*)(y + (size_t)p0.x*128))[lane];
    float2 x1 = ((const float2*)(y + (size_t)p1.x*128))[lane];
    float2 x2 = ((const float2*)(y + (size_t)p2.x*128))[lane];
    float2 x3 = ((const float2*)(y + (size_t)p3.x*128))[lane];
    float v0 = __int_as_float(p0.y), v1 = __int_as_float(p1.y);
    float v2 = __int_as_float(p2.y), v3 = __int_as_float(p3.y);
    a0.x = fmaf(v0, x0.x, a0.x); a0.y = fmaf(v0, x0.y, a0.y);
    a1.x = fmaf(v1, x1.x, a1.x); a1.y = fmaf(v1, x1.y, a1.y);
    a2.x = fmaf(v2, x2.x, a2.x); a2.y = fmaf(v2, x2.y, a2.y);
    a3.x = fmaf(v3, x3.x, a3.x); a3.y = fmaf(v3, x3.y, a3.y);
  }
  for(; i < e; i++){
    int2 p = pairs[i];
    float v = __int_as_float(p.y);
    float2 xv = ((const float2*)(y + (size_t)p.x*128))[lane];
    a0.x = fmaf(v, xv.x, a0.x); a0.y = fmaf(v, xv.y, a0.y);
  }
  float2 acc = make_float2((a0.x+a1.x)+(a2.x+a3.x), (a0.y+a1.y)+(a2.y+a3.y));
  float2 b = ((const float2*)bias)[lane];
  acc.x = fmaxf(acc.x + b.x, 0.f);
  acc.y = fmaxf(acc.y + b.y, 0.f);
  ((float2*)(h + (size_t)wid*128))[lane] = acc;
}

// ---------------- SpMM + bias + relu + head dot, fused: z[r] = relu(A y + b) . Wout ----------------
__global__ __launch_bounds__(256) void k_spmm_head(const int* __restrict__ row_ptr,
                                                   const int2* __restrict__ pairs,
                                                   const float* __restrict__ y,
                                                   const float* __restrict__ bias,
                                                   const float* __restrict__ Wout,
                                                   float* __restrict__ z, int n){
  int wid  = (int)((blockIdx.x*(size_t)blockDim.x + threadIdx.x) >> 6);
  int lane = threadIdx.x & 63;
  if(wid >= n) return;
  int s = row_ptr[wid], e = row_ptr[wid+1];
  float2 a0 = make_float2(0.f,0.f), a1 = a0, a2 = a0, a3 = a0;
  int i = s;
  for(; i+4 <= e; i += 4){
    int2 p0 = pairs[i],   p1 = pairs[i+1], p2 = pairs[i+2], p3 = pairs[i+3];
    float2 x0 = ((const float2*)(y + (size_t)p0.x*128))[lane];
    float2 x1 = ((const float2*)(y + (size_t)p1.x*128))[lane];
    float2 x2 = ((const float2*)(y + (size_t)p2.x*128))[lane];
    float2 x3 = ((const float2*)(y + (size_t)p3.x*128))[lane];
    float v0 = __int_as_float(p0.y), v1 = __int_as_float(p1.y);
    float v2 = __int_as_float(p2.y), v3 = __int_as_float(p3.y);
    a0.x = fmaf(v0, x0.x, a0.x); a0.y = fmaf(v0, x0.y, a0.y);
    a1.x = fmaf(v1, x1.x, a1.x); a1.y = fmaf(v1, x1.y, a1.y);
    a2.x = fmaf(v2, x2.x, a2.x); a2.y = fmaf(v2, x2.y, a2.y);
    a3.x = fmaf(v3, x3.x, a3.x); a3.y = fmaf(v3, x3.y, a3.y);
  }
  for(; i < e; i++){
    int2 p = pairs[i];
    float v = __int_as_float(p.y);
    float2 xv = ((const float2*)(y + (size_t)p.x*128))[lane];
    a0.x = fmaf(v, xv.x, a0.x); a0.y = fmaf(v, xv.y, a0.y);
  }
  float2 acc = make_float2((a0.x+a1.x)+(a2.x+a3.x), (a0.y+a1.y)+(a2.y+a3.y));
  float2 b  = ((const float2*)bias)[lane];
  float2 wv = ((const float2*)Wout)[lane];
  float hx = fmaxf(acc.x + b.x, 0.f);
  float hy = fmaxf(acc.y + b.y, 0.f);
  float p = hx*wv.x + hy*wv.y;
  #pragma unroll
  for(int off=32; off; off>>=1) p += __shfl_down(p, off);
  if(lane==0) z[wid] = p;
}

// ---------------- final: out[r] = softplus(sum val*z[col] + bout) ----------------
__global__ void k_spmm1_softplus(const int* __restrict__ row_ptr,
                                 const int2* __restrict__ pairs,
                                 const float* __restrict__ z,
                                 const float* __restrict__ bout,
                                 float* __restrict__ out, int n){
  int r = blockIdx.x*256 + threadIdx.x;
  if(r >= n) return;
  int s = row_ptr[r], e = row_ptr[r+1];
  float a0=0.f, a1=0.f, a2=0.f, a3=0.f;
  int i = s;
  for(; i+4 <= e; i += 4){
    int2 p0 = pairs[i],   p1 = pairs[i+1], p2 = pairs[i+2], p3 = pairs[i+3];
    a0 = fmaf(__int_as_float(p0.y), z[p0.x], a0);
    a1 = fmaf(__int_as_float(p1.y), z[p1.x], a1);
    a2 = fmaf(__int_as_float(p2.y), z[p2.x], a2);
    a3 = fmaf(__int_as_float(p3.y), z[p3.x], a3);
  }
  for(; i < e; i++){
    int2 p = pairs[i];
    a0 = fmaf(__int_as_float(p.y), z[p.x], a0);
  }
  float x = (a0+a1)+(a2+a3) + bout[0];
  out[r] = fmaxf(x, 0.f) + log1pf(expf(-fabsf(x)));   // stable softplus
}

extern "C" void kernel_launch(void* const* d_in, const int* in_sizes, int n_in,
                              void* d_out, int out_size, void* d_ws, size_t ws_size,
                              hipStream_t stream){
  const float* x    = (const float*)d_in[0];
  const int*   erow = (const int*)d_in[1];
  const int*   ecol = (const int*)d_in[2];
  const float* eval = (const float*)d_in[3];
  const float* W1   = (const float*)d_in[4];
  const float* b1   = (const float*)d_in[5];
  const float* W2   = (const float*)d_in[6];
  const float* b2   = (const float*)d_in[7];
  const float* Wout = (const float*)d_in[8];
  const float* bout = (const float*)d_in[9];
  float* out = (float*)d_out;

  const int N = in_sizes[0] / 128;   // 100000
  const int E = in_sizes[1];         // 1600000

  char* p = (char*)d_ws;
  auto alloc = [&](size_t bytes)->char*{
    char* r = p; p += (bytes + 255) & ~(size_t)255; return r;
  };
  int*   cnt     = (int*)  alloc((size_t)N*4);
  int*   row_ptr = (int*)  alloc((size_t)(N+1)*4);
  int*   offs    = (int*)  alloc((size_t)N*4);
  int*   scanned = (int*)  alloc((size_t)N*4);
  int*   sums    = (int*)  alloc(4096);
  int2*  pairs   = (int2*) alloc((size_t)E*8);
  float* ybuf    = (float*)alloc((size_t)N*128*4);
  float* hbuf    = (float*)alloc((size_t)N*128*4);
  float* z       = (float*)alloc((size_t)N*4);

  // CSR build
  hipMemsetAsync(cnt, 0, (size_t)N*4, stream);
  k_hist<<<(E+255)/256, 256, 0, stream>>>(erow, cnt, E);
  int ntiles = (N+1023)/1024;
  k_scan1<<<ntiles, 1024, 0, stream>>>(cnt, scanned, sums, N);
  k_scan2<<<1, 64, 0, stream>>>(sums, ntiles);
  k_scan3<<<(N+1+255)/256, 256, 0, stream>>>(scanned, sums, row_ptr, offs, N, E);
  k_scatter<<<(E+255)/256, 256, 0, stream>>>(erow, ecol, eval, offs, pairs, E);

  // layer 1: y = x@W1 ; h = relu(A y + b1)
  k_gemm<<<(N+127)/128, 256, 0, stream>>>(x, W1, ybuf, N);
  k_spmm_relu<<<(N+3)/4, 256, 0, stream>>>(row_ptr, pairs, ybuf, b1, hbuf, N);
  // layer 2: y = h@W2 ; z = relu(A y + b2) . Wout   (head fused into spmm)
  k_gemm<<<(N+127)/128, 256, 0, stream>>>(hbuf, W2, ybuf, N);
  k_spmm_head<<<(N+3)/4, 256, 0, stream>>>(row_ptr, pairs, ybuf, b2, Wout, z, N);
  // out = softplus(A z + bout)
  k_spmm1_softplus<<<(N+255)/256, 256, 0, stream>>>(row_ptr, pairs, z, bout, out, N);
}

// Round 8
// 628.648 us; speedup vs baseline: 1.0112x; 1.0112x over previous
//
#include <hip/hip_runtime.h>
#include <math.h>

// SimpleGNN: out = softplus(A(relu(A(relu(A(x W1)+b1) W2)+b2) Wout)+bout)
// using spmm(x) @ W == spmm(x @ W) to make the last spmm D=1.
// CSR edges stored as packed (col,val) int2 pairs -> single 8B store in scatter.
// Scatter reads use non-temporal loads so pairs[] lines survive in L2 and
// write-merge (8 pairs / 64B line) before HBM eviction.

// ---------------- CSR build ----------------
__global__ void k_hist(const int* __restrict__ row, int* __restrict__ cnt, int E){
  int e = blockIdx.x*256 + threadIdx.x;
  if(e < E) atomicAdd(&cnt[__builtin_nontemporal_load(&row[e])], 1);
}

// per-tile exclusive scan (tile=1024); writes local-exclusive values + tile totals
__global__ void k_scan1(const int* __restrict__ cnt, int* __restrict__ scanned,
                        int* __restrict__ sums, int n){
  __shared__ int tmp[1024];
  int i = blockIdx.x*1024 + threadIdx.x;
  int v = (i<n)? cnt[i] : 0;
  tmp[threadIdx.x] = v;
  __syncthreads();
  for(int off=1; off<1024; off<<=1){
    int t = (threadIdx.x>=off)? tmp[threadIdx.x-off] : 0;
    __syncthreads();
    tmp[threadIdx.x] += t;
    __syncthreads();
  }
  if(i<n) scanned[i] = tmp[threadIdx.x] - v;      // local exclusive
  if(threadIdx.x==1023) sums[blockIdx.x] = tmp[1023];
}

__global__ void k_scan2(int* sums, int ntiles){
  if(threadIdx.x==0 && blockIdx.x==0){
    int acc=0;
    for(int i=0;i<ntiles;i++){ int v=sums[i]; sums[i]=acc; acc+=v; }
  }
}

__global__ void k_scan3(const int* __restrict__ scanned, const int* __restrict__ sums,
                        int* __restrict__ row_ptr, int* __restrict__ offs, int n, int E){
  int i = blockIdx.x*256 + threadIdx.x;
  if(i<n){ int ex = scanned[i] + sums[i>>10]; row_ptr[i]=ex; offs[i]=ex; }
  else if(i==n){ row_ptr[n]=E; }
}

// packed scatter: one 8B store per edge; nt loads keep streams out of L2
__global__ void k_scatter(const int* __restrict__ row, const int* __restrict__ col,
                          const float* __restrict__ val, int* __restrict__ offs,
                          int2* __restrict__ pairs, int E){
  int e = blockIdx.x*256 + threadIdx.x;
  if(e<E){
    int r = __builtin_nontemporal_load(&row[e]);
    int c = __builtin_nontemporal_load(&col[e]);
    float v = __builtin_nontemporal_load(&val[e]);
    int p = atomicAdd(&offs[r],1);
    pairs[p] = make_int2(c, __float_as_int(v));
  }
}

// ---------------- dense GEMM: Y[n,128] = X[n,128] @ W[128,128] ----------------
// 128x128 block tile, BK=32, 256 threads, 8x8 per-thread register tile.
__global__ __launch_bounds__(256) void k_gemm(const float* __restrict__ X,
                                              const float* __restrict__ W,
                                              float* __restrict__ Y, int n){
  __shared__ float xs_t[32][128];   // [k][row] transposed x tile
  __shared__ float ws[32][128];     // [k][col]
  const int t   = threadIdx.x;
  const int row0 = blockIdx.x * 128;
  const int cg  = t & 15;           // col group: cols cg*8 .. cg*8+7
  const int rg  = t >> 4;           // row group: rows rg*8 .. rg*8+7

  float acc[8][8];
  #pragma unroll
  for(int i=0;i<8;i++)
    #pragma unroll
    for(int j=0;j<8;j++) acc[i][j]=0.f;

  for(int kt=0; kt<128; kt+=32){
    // stage x transposed: thread -> row r = t>>1, half q = t&1 (16 floats)
    {
      int r = t>>1, q = t&1;
      int gr = row0 + r;
      float4 a = make_float4(0,0,0,0), b = a, c = a, d = a;
      if(gr < n){
        const float4* src = (const float4*)(X + (size_t)gr*128 + kt + q*16);
        a = src[0]; b = src[1]; c = src[2]; d = src[3];
      }
      int kb = q*16;
      xs_t[kb+ 0][r]=a.x; xs_t[kb+ 1][r]=a.y; xs_t[kb+ 2][r]=a.z; xs_t[kb+ 3][r]=a.w;
      xs_t[kb+ 4][r]=b.x; xs_t[kb+ 5][r]=b.y; xs_t[kb+ 6][r]=b.z; xs_t[kb+ 7][r]=b.w;
      xs_t[kb+ 8][r]=c.x; xs_t[kb+ 9][r]=c.y; xs_t[kb+10][r]=c.z; xs_t[kb+11][r]=c.w;
      xs_t[kb+12][r]=d.x; xs_t[kb+13][r]=d.y; xs_t[kb+14][r]=d.z; xs_t[kb+15][r]=d.w;
    }
    // stage W: linear float4 mapping (coalesced, conflict-free)
    #pragma unroll
    for(int rep=0; rep<4; rep++){
      int f  = t + rep*256;        // float4 index in [0,1024)
      int kr = f >> 5;             // 32 float4 per k-row
      int cq = f & 31;
      float4 w = *(const float4*)(W + (size_t)(kt+kr)*128 + cq*4);
      *(float4*)&ws[kr][cq*4] = w;
    }
    __syncthreads();

    #pragma unroll
    for(int kk=0; kk<32; kk++){
      float4 wv0 = *(const float4*)&ws[kk][cg*8];
      float4 wv1 = *(const float4*)&ws[kk][cg*8+4];
      #pragma unroll
      for(int i=0;i<8;i++){
        float xv = xs_t[kk][rg*8+i];
        acc[i][0] = fmaf(xv, wv0.x, acc[i][0]);
        acc[i][1] = fmaf(xv, wv0.y, acc[i][1]);
        acc[i][2] = fmaf(xv, wv0.z, acc[i][2]);
        acc[i][3] = fmaf(xv, wv0.w, acc[i][3]);
        acc[i][4] = fmaf(xv, wv1.x, acc[i][4]);
        acc[i][5] = fmaf(xv, wv1.y, acc[i][5]);
        acc[i][6] = fmaf(xv, wv1.z, acc[i][6]);
        acc[i][7] = fmaf(xv, wv1.w, acc[i][7]);
      }
    }
    __syncthreads();
  }

  #pragma unroll
  for(int i=0;i<8;i++){
    int gr = row0 + rg*8 + i;
    if(gr < n){
      float* dst = Y + (size_t)gr*128 + cg*8;
      *(float4*)dst     = make_float4(acc[i][0],acc[i][1],acc[i][2],acc[i][3]);
      *(float4*)(dst+4) = make_float4(acc[i][4],acc[i][5],acc[i][6],acc[i][7]);
    }
  }
}

// ---------------- SpMM (D=128) + bias + relu: h[r] = relu(sum val*y[col] + b) ----------------
// one wave per row, float2 per lane, 4-wide edge unroll for ILP (4 gathers in flight)
__global__ __launch_bounds__(256) void k_spmm_relu(const int* __restrict__ row_ptr,
                                                   const int2* __restrict__ pairs,
                                                   const float* __restrict__ y,
                                                   const float* __restrict__ bias,
                                                   float* __restrict__ h, int n){
  int wid  = (int)((blockIdx.x*(size_t)blockDim.x + threadIdx.x) >> 6);
  int lane = threadIdx.x & 63;
  if(wid >= n) return;
  int s = row_ptr[wid], e = row_ptr[wid+1];
  float2 a0 = make_float2(0.f,0.f), a1 = a0, a2 = a0, a3 = a0;
  int i = s;
  for(; i+4 <= e; i += 4){
    int2 p0 = pairs[i],   p1 = pairs[i+1], p2 = pairs[i+2], p3 = pairs[i+3];
    float2 x0 = ((const float2*)(y + (size_t)p0.x*128))[lane];
    float2 x1 = ((const float2*)(y + (size_t)p1.x*128))[lane];
    float2 x2 = ((const float2*)(y + (size_t)p2.x*128))[lane];
    float2 x3 = ((const float2*)(y + (size_t)p3.x*128))[lane];
    float v0 = __int_as_float(p0.y), v1 = __int_as_float(p1.y);
    float v2 = __int_as_float(p2.y), v3 = __int_as_float(p3.y);
    a0.x = fmaf(v0, x0.x, a0.x); a0.y = fmaf(v0, x0.y, a0.y);
    a1.x = fmaf(v1, x1.x, a1.x); a1.y = fmaf(v1, x1.y, a1.y);
    a2.x = fmaf(v2, x2.x, a2.x); a2.y = fmaf(v2, x2.y, a2.y);
    a3.x = fmaf(v3, x3.x, a3.x); a3.y = fmaf(v3, x3.y, a3.y);
  }
  for(; i < e; i++){
    int2 p = pairs[i];
    float v = __int_as_float(p.y);
    float2 xv = ((const float2*)(y + (size_t)p.x*128))[lane];
    a0.x = fmaf(v, xv.x, a0.x); a0.y = fmaf(v, xv.y, a0.y);
  }
  float2 acc = make_float2((a0.x+a1.x)+(a2.x+a3.x), (a0.y+a1.y)+(a2.y+a3.y));
  float2 b = ((const float2*)bias)[lane];
  acc.x = fmaxf(acc.x + b.x, 0.f);
  acc.y = fmaxf(acc.y + b.y, 0.f);
  ((float2*)(h + (size_t)wid*128))[lane] = acc;
}

// ---------------- SpMM + bias + relu + head dot, fused: z[r] = relu(A y + b) . Wout ----------------
__global__ __launch_bounds__(256) void k_spmm_head(const int* __restrict__ row_ptr,
                                                   const int2* __restrict__ pairs,
                                                   const float* __restrict__ y,
                                                   const float* __restrict__ bias,
                                                   const float* __restrict__ Wout,
                                                   float* __restrict__ z, int n){
  int wid  = (int)((blockIdx.x*(size_t)blockDim.x + threadIdx.x) >> 6);
  int lane = threadIdx.x & 63;
  if(wid >= n) return;
  int s = row_ptr[wid], e = row_ptr[wid+1];
  float2 a0 = make_float2(0.f,0.f), a1 = a0, a2 = a0, a3 = a0;
  int i = s;
  for(; i+4 <= e; i += 4){
    int2 p0 = pairs[i],   p1 = pairs[i+1], p2 = pairs[i+2], p3 = pairs[i+3];
    float2 x0 = ((const float2*)(y + (size_t)p0.x*128))[lane];
    float2 x1 = ((const float2*)(y + (size_t)p1.x*128))[lane];
    float2 x2 = ((const float2*)(y + (size_t)p2.x*128))[lane];
    float2 x3 = ((const float2*)(y + (size_t)p3.x*128))[lane];
    float v0 = __int_as_float(p0.y), v1 = __int_as_float(p1.y);
    float v2 = __int_as_float(p2.y), v3 = __int_as_float(p3.y);
    a0.x = fmaf(v0, x0.x, a0.x); a0.y = fmaf(v0, x0.y, a0.y);
    a1.x = fmaf(v1, x1.x, a1.x); a1.y = fmaf(v1, x1.y, a1.y);
    a2.x = fmaf(v2, x2.x, a2.x); a2.y = fmaf(v2, x2.y, a2.y);
    a3.x = fmaf(v3, x3.x, a3.x); a3.y = fmaf(v3, x3.y, a3.y);
  }
  for(; i < e; i++){
    int2 p = pairs[i];
    float v = __int_as_float(p.y);
    float2 xv = ((const float2*)(y + (size_t)p.x*128))[lane];
    a0.x = fmaf(v, xv.x, a0.x); a0.y = fmaf(v, xv.y, a0.y);
  }
  float2 acc = make_float2((a0.x+a1.x)+(a2.x+a3.x), (a0.y+a1.y)+(a2.y+a3.y));
  float2 b  = ((const float2*)bias)[lane];
  float2 wv = ((const float2*)Wout)[lane];
  float hx = fmaxf(acc.x + b.x, 0.f);
  float hy = fmaxf(acc.y + b.y, 0.f);
  float p = hx*wv.x + hy*wv.y;
  #pragma unroll
  for(int off=32; off; off>>=1) p += __shfl_down(p, off);
  if(lane==0) z[wid] = p;
}

// ---------------- final: out[r] = softplus(sum val*z[col] + bout) ----------------
__global__ void k_spmm1_softplus(const int* __restrict__ row_ptr,
                                 const int2* __restrict__ pairs,
                                 const float* __restrict__ z,
                                 const float* __restrict__ bout,
                                 float* __restrict__ out, int n){
  int r = blockIdx.x*256 + threadIdx.x;
  if(r >= n) return;
  int s = row_ptr[r], e = row_ptr[r+1];
  float a0=0.f, a1=0.f, a2=0.f, a3=0.f;
  int i = s;
  for(; i+4 <= e; i += 4){
    int2 p0 = pairs[i],   p1 = pairs[i+1], p2 = pairs[i+2], p3 = pairs[i+3];
    a0 = fmaf(__int_as_float(p0.y), z[p0.x], a0);
    a1 = fmaf(__int_as_float(p1.y), z[p1.x], a1);
    a2 = fmaf(__int_as_float(p2.y), z[p2.x], a2);
    a3 = fmaf(__int_as_float(p3.y), z[p3.x], a3);
  }
  for(; i < e; i++){
    int2 p = pairs[i];
    a0 = fmaf(__int_as_float(p.y), z[p.x], a0);
  }
  float x = (a0+a1)+(a2+a3) + bout[0];
  out[r] = fmaxf(x, 0.f) + log1pf(expf(-fabsf(x)));   // stable softplus
}

extern "C" void kernel_launch(void* const* d_in, const int* in_sizes, int n_in,
                              void* d_out, int out_size, void* d_ws, size_t ws_size,
                              hipStream_t stream){
  const float* x    = (const float*)d_in[0];
  const int*   erow = (const int*)d_in[1];
  const int*   ecol = (const int*)d_in[2];
  const float* eval = (const float*)d_in[3];
  const float* W1   = (const float*)d_in[4];
  const float* b1   = (const float*)d_in[5];
  const float* W2   = (const float*)d_in[6];
  const float* b2   = (const float*)d_in[7];
  const float* Wout = (const float*)d_in[8];
  const float* bout = (const float*)d_in[9];
  float* out = (float*)d_out;

  const int N = in_sizes[0] / 128;   // 100000
  const int E = in_sizes[1];         // 1600000

  char* p = (char*)d_ws;
  auto alloc = [&](size_t bytes)->char*{
    char* r = p; p += (bytes + 255) & ~(size_t)255; return r;
  };
  int*   cnt     = (int*)  alloc((size_t)N*4);
  int*   row_ptr = (int*)  alloc((size_t)(N+1)*4);
  int*   offs    = (int*)  alloc((size_t)N*4);
  int*   scanned = (int*)  alloc((size_t)N*4);
  int*   sums    = (int*)  alloc(4096);
  int2*  pairs   = (int2*) alloc((size_t)E*8);
  float* ybuf    = (float*)alloc((size_t)N*128*4);
  float* hbuf    = (float*)alloc((size_t)N*128*4);
  float* z       = (float*)alloc((size_t)N*4);

  // CSR build
  hipMemsetAsync(cnt, 0, (size_t)N*4, stream);
  k_hist<<<(E+255)/256, 256, 0, stream>>>(erow, cnt, E);
  int ntiles = (N+1023)/1024;
  k_scan1<<<ntiles, 1024, 0, stream>>>(cnt, scanned, sums, N);
  k_scan2<<<1, 64, 0, stream>>>(sums, ntiles);
  k_scan3<<<(N+1+255)/256, 256, 0, stream>>>(scanned, sums, row_ptr, offs, N, E);
  k_scatter<<<(E+255)/256, 256, 0, stream>>>(erow, ecol, eval, offs, pairs, E);

  // layer 1: y = x@W1 ; h = relu(A y + b1)
  k_gemm<<<(N+127)/128, 256, 0, stream>>>(x, W1, ybuf, N);
  k_spmm_relu<<<(N+3)/4, 256, 0, stream>>>(row_ptr, pairs, ybuf, b1, hbuf, N);
  // layer 2: y = h@W2 ; z = relu(A y + b2) . Wout   (head fused into spmm)
  k_gemm<<<(N+127)/128, 256, 0, stream>>>(hbuf, W2, ybuf, N);
  k_spmm_head<<<(N+3)/4, 256, 0, stream>>>(row_ptr, pairs, ybuf, b2, Wout, z, N);
  // out = softplus(A z + bout)
  k_spmm1_softplus<<<(N+255)/256, 256, 0, stream>>>(row_ptr, pairs, z, bout, out, N);
}

// Round 9
// 551.120 us; speedup vs baseline: 1.1535x; 1.1407x over previous
//
#include <hip/hip_runtime.h>
#include <math.h>

// SimpleGNN: out = softplus(A(relu(A(relu(A(x W1)+b1) W2)+b2) Wout)+bout)
// using spmm(x) @ W == spmm(x @ W) to make the last spmm D=1.
// CSR edges as packed (col,val) int2. All N x 128 intermediates stored bf16
// (fp32 accumulation) to halve SpMM gather / write traffic.

typedef unsigned int u32;
typedef unsigned short u16;

__device__ inline float bf2f(u32 lo16){ return __uint_as_float(lo16 << 16); }
__device__ inline u32 f2bf(float f){            // round-to-nearest-even
  u32 t = __float_as_uint(f);
  return (t + 0x7FFFu + ((t >> 16) & 1u)) >> 16;
}

// ---------------- CSR build ----------------
__global__ void k_hist(const int* __restrict__ row, int* __restrict__ cnt, int E){
  int e = blockIdx.x*256 + threadIdx.x;
  if(e < E) atomicAdd(&cnt[__builtin_nontemporal_load(&row[e])], 1);
}

__global__ void k_scan1(const int* __restrict__ cnt, int* __restrict__ scanned,
                        int* __restrict__ sums, int n){
  __shared__ int tmp[1024];
  int i = blockIdx.x*1024 + threadIdx.x;
  int v = (i<n)? cnt[i] : 0;
  tmp[threadIdx.x] = v;
  __syncthreads();
  for(int off=1; off<1024; off<<=1){
    int t = (threadIdx.x>=off)? tmp[threadIdx.x-off] : 0;
    __syncthreads();
    tmp[threadIdx.x] += t;
    __syncthreads();
  }
  if(i<n) scanned[i] = tmp[threadIdx.x] - v;
  if(threadIdx.x==1023) sums[blockIdx.x] = tmp[1023];
}

__global__ void k_scan2(int* sums, int ntiles){
  if(threadIdx.x==0 && blockIdx.x==0){
    int acc=0;
    for(int i=0;i<ntiles;i++){ int v=sums[i]; sums[i]=acc; acc+=v; }
  }
}

__global__ void k_scan3(const int* __restrict__ scanned, const int* __restrict__ sums,
                        int* __restrict__ row_ptr, int* __restrict__ offs, int n, int E){
  int i = blockIdx.x*256 + threadIdx.x;
  if(i<n){ int ex = scanned[i] + sums[i>>10]; row_ptr[i]=ex; offs[i]=ex; }
  else if(i==n){ row_ptr[n]=E; }
}

__global__ void k_scatter(const int* __restrict__ row, const int* __restrict__ col,
                          const float* __restrict__ val, int* __restrict__ offs,
                          int2* __restrict__ pairs, int E){
  int e = blockIdx.x*256 + threadIdx.x;
  if(e<E){
    int r = __builtin_nontemporal_load(&row[e]);
    int c = __builtin_nontemporal_load(&col[e]);
    float v = __builtin_nontemporal_load(&val[e]);
    int p = atomicAdd(&offs[r],1);
    pairs[p] = make_int2(c, __float_as_int(v));
  }
}

// ---------------- dense GEMM: Y[n,128](bf16) = X[n,128] @ W[128,128] ----------------
// A_BF16: X is bf16 (ushort*), else fp32. Output always bf16. fp32 math.
template<bool A_BF16>
__global__ __launch_bounds__(256) void k_gemm(const void* __restrict__ Xv,
                                              const float* __restrict__ W,
                                              u16* __restrict__ Y, int n){
  __shared__ float xs_t[32][128];   // [k][row]
  __shared__ float ws[32][128];     // [k][col]
  const int t    = threadIdx.x;
  const int row0 = blockIdx.x * 128;
  const int cg   = t & 15;
  const int rg   = t >> 4;

  float acc[8][8];
  #pragma unroll
  for(int i=0;i<8;i++)
    #pragma unroll
    for(int j=0;j<8;j++) acc[i][j]=0.f;

  for(int kt=0; kt<128; kt+=32){
    {
      int r = t>>1, q = t&1;
      int gr = row0 + r;
      int kb = q*16;
      if(A_BF16){
        const u16* Xb = (const u16*)Xv;
        uint4 a = make_uint4(0,0,0,0), b = a;
        if(gr < n){
          const uint4* src = (const uint4*)(Xb + (size_t)gr*128 + kt + q*16);
          a = src[0]; b = src[1];
        }
        xs_t[kb+ 0][r]=bf2f(a.x&0xffff); xs_t[kb+ 1][r]=bf2f(a.x>>16);
        xs_t[kb+ 2][r]=bf2f(a.y&0xffff); xs_t[kb+ 3][r]=bf2f(a.y>>16);
        xs_t[kb+ 4][r]=bf2f(a.z&0xffff); xs_t[kb+ 5][r]=bf2f(a.z>>16);
        xs_t[kb+ 6][r]=bf2f(a.w&0xffff); xs_t[kb+ 7][r]=bf2f(a.w>>16);
        xs_t[kb+ 8][r]=bf2f(b.x&0xffff); xs_t[kb+ 9][r]=bf2f(b.x>>16);
        xs_t[kb+10][r]=bf2f(b.y&0xffff); xs_t[kb+11][r]=bf2f(b.y>>16);
        xs_t[kb+12][r]=bf2f(b.z&0xffff); xs_t[kb+13][r]=bf2f(b.z>>16);
        xs_t[kb+14][r]=bf2f(b.w&0xffff); xs_t[kb+15][r]=bf2f(b.w>>16);
      }else{
        const float* Xf = (const float*)Xv;
        float4 a = make_float4(0,0,0,0), b = a, c = a, d = a;
        if(gr < n){
          const float4* src = (const float4*)(Xf + (size_t)gr*128 + kt + q*16);
          a = src[0]; b = src[1]; c = src[2]; d = src[3];
        }
        xs_t[kb+ 0][r]=a.x; xs_t[kb+ 1][r]=a.y; xs_t[kb+ 2][r]=a.z; xs_t[kb+ 3][r]=a.w;
        xs_t[kb+ 4][r]=b.x; xs_t[kb+ 5][r]=b.y; xs_t[kb+ 6][r]=b.z; xs_t[kb+ 7][r]=b.w;
        xs_t[kb+ 8][r]=c.x; xs_t[kb+ 9][r]=c.y; xs_t[kb+10][r]=c.z; xs_t[kb+11][r]=c.w;
        xs_t[kb+12][r]=d.x; xs_t[kb+13][r]=d.y; xs_t[kb+14][r]=d.z; xs_t[kb+15][r]=d.w;
      }
    }
    #pragma unroll
    for(int rep=0; rep<4; rep++){
      int f  = t + rep*256;
      int kr = f >> 5;
      int cq = f & 31;
      float4 w = *(const float4*)(W + (size_t)(kt+kr)*128 + cq*4);
      *(float4*)&ws[kr][cq*4] = w;
    }
    __syncthreads();

    #pragma unroll
    for(int kk=0; kk<32; kk++){
      float4 wv0 = *(const float4*)&ws[kk][cg*8];
      float4 wv1 = *(const float4*)&ws[kk][cg*8+4];
      #pragma unroll
      for(int i=0;i<8;i++){
        float xv = xs_t[kk][rg*8+i];
        acc[i][0] = fmaf(xv, wv0.x, acc[i][0]);
        acc[i][1] = fmaf(xv, wv0.y, acc[i][1]);
        acc[i][2] = fmaf(xv, wv0.z, acc[i][2]);
        acc[i][3] = fmaf(xv, wv0.w, acc[i][3]);
        acc[i][4] = fmaf(xv, wv1.x, acc[i][4]);
        acc[i][5] = fmaf(xv, wv1.y, acc[i][5]);
        acc[i][6] = fmaf(xv, wv1.z, acc[i][6]);
        acc[i][7] = fmaf(xv, wv1.w, acc[i][7]);
      }
    }
    __syncthreads();
  }

  #pragma unroll
  for(int i=0;i<8;i++){
    int gr = row0 + rg*8 + i;
    if(gr < n){
      u32 w0 = f2bf(acc[i][0]) | (f2bf(acc[i][1])<<16);
      u32 w1 = f2bf(acc[i][2]) | (f2bf(acc[i][3])<<16);
      u32 w2 = f2bf(acc[i][4]) | (f2bf(acc[i][5])<<16);
      u32 w3 = f2bf(acc[i][6]) | (f2bf(acc[i][7])<<16);
      *(uint4*)(Y + (size_t)gr*128 + cg*8) = make_uint4(w0,w1,w2,w3);
    }
  }
}

// ---------------- SpMM (D=128 bf16) + bias + relu -> bf16 ----------------
// one wave per row, 2 bf16 (one dword) per lane, 4-wide edge unroll
__global__ __launch_bounds__(256) void k_spmm_relu(const int* __restrict__ row_ptr,
                                                   const int2* __restrict__ pairs,
                                                   const u16* __restrict__ y,
                                                   const float* __restrict__ bias,
                                                   u16* __restrict__ h, int n){
  int wid  = (int)((blockIdx.x*(size_t)blockDim.x + threadIdx.x) >> 6);
  int lane = threadIdx.x & 63;
  if(wid >= n) return;
  int s = row_ptr[wid], e = row_ptr[wid+1];
  float ax0=0.f, ay0=0.f, ax1=0.f, ay1=0.f, ax2=0.f, ay2=0.f, ax3=0.f, ay3=0.f;
  int i = s;
  for(; i+4 <= e; i += 4){
    int2 p0 = pairs[i], p1 = pairs[i+1], p2 = pairs[i+2], p3 = pairs[i+3];
    u32 w0 = ((const u32*)(y + (size_t)p0.x*128))[lane];
    u32 w1 = ((const u32*)(y + (size_t)p1.x*128))[lane];
    u32 w2 = ((const u32*)(y + (size_t)p2.x*128))[lane];
    u32 w3 = ((const u32*)(y + (size_t)p3.x*128))[lane];
    float v0 = __int_as_float(p0.y), v1 = __int_as_float(p1.y);
    float v2 = __int_as_float(p2.y), v3 = __int_as_float(p3.y);
    ax0 = fmaf(v0, bf2f(w0&0xffff), ax0); ay0 = fmaf(v0, bf2f(w0>>16), ay0);
    ax1 = fmaf(v1, bf2f(w1&0xffff), ax1); ay1 = fmaf(v1, bf2f(w1>>16), ay1);
    ax2 = fmaf(v2, bf2f(w2&0xffff), ax2); ay2 = fmaf(v2, bf2f(w2>>16), ay2);
    ax3 = fmaf(v3, bf2f(w3&0xffff), ax3); ay3 = fmaf(v3, bf2f(w3>>16), ay3);
  }
  for(; i < e; i++){
    int2 p = pairs[i];
    float v = __int_as_float(p.y);
    u32 w = ((const u32*)(y + (size_t)p.x*128))[lane];
    ax0 = fmaf(v, bf2f(w&0xffff), ax0); ay0 = fmaf(v, bf2f(w>>16), ay0);
  }
  float accx = (ax0+ax1)+(ax2+ax3);
  float accy = (ay0+ay1)+(ay2+ay3);
  float2 b = ((const float2*)bias)[lane];
  accx = fmaxf(accx + b.x, 0.f);
  accy = fmaxf(accy + b.y, 0.f);
  ((u32*)(h + (size_t)wid*128))[lane] = f2bf(accx) | (f2bf(accy)<<16);
}

// ---------------- SpMM(bf16) + bias + relu + head dot, fused -> z fp32 ----------------
__global__ __launch_bounds__(256) void k_spmm_head(const int* __restrict__ row_ptr,
                                                   const int2* __restrict__ pairs,
                                                   const u16* __restrict__ y,
                                                   const float* __restrict__ bias,
                                                   const float* __restrict__ Wout,
                                                   float* __restrict__ z, int n){
  int wid  = (int)((blockIdx.x*(size_t)blockDim.x + threadIdx.x) >> 6);
  int lane = threadIdx.x & 63;
  if(wid >= n) return;
  int s = row_ptr[wid], e = row_ptr[wid+1];
  float ax0=0.f, ay0=0.f, ax1=0.f, ay1=0.f, ax2=0.f, ay2=0.f, ax3=0.f, ay3=0.f;
  int i = s;
  for(; i+4 <= e; i += 4){
    int2 p0 = pairs[i], p1 = pairs[i+1], p2 = pairs[i+2], p3 = pairs[i+3];
    u32 w0 = ((const u32*)(y + (size_t)p0.x*128))[lane];
    u32 w1 = ((const u32*)(y + (size_t)p1.x*128))[lane];
    u32 w2 = ((const u32*)(y + (size_t)p2.x*128))[lane];
    u32 w3 = ((const u32*)(y + (size_t)p3.x*128))[lane];
    float v0 = __int_as_float(p0.y), v1 = __int_as_float(p1.y);
    float v2 = __int_as_float(p2.y), v3 = __int_as_float(p3.y);
    ax0 = fmaf(v0, bf2f(w0&0xffff), ax0); ay0 = fmaf(v0, bf2f(w0>>16), ay0);
    ax1 = fmaf(v1, bf2f(w1&0xffff), ax1); ay1 = fmaf(v1, bf2f(w1>>16), ay1);
    ax2 = fmaf(v2, bf2f(w2&0xffff), ax2); ay2 = fmaf(v2, bf2f(w2>>16), ay2);
    ax3 = fmaf(v3, bf2f(w3&0xffff), ax3); ay3 = fmaf(v3, bf2f(w3>>16), ay3);
  }
  for(; i < e; i++){
    int2 p = pairs[i];
    float v = __int_as_float(p.y);
    u32 w = ((const u32*)(y + (size_t)p.x*128))[lane];
    ax0 = fmaf(v, bf2f(w&0xffff), ax0); ay0 = fmaf(v, bf2f(w>>16), ay0);
  }
  float accx = (ax0+ax1)+(ax2+ax3);
  float accy = (ay0+ay1)+(ay2+ay3);
  float2 b  = ((const float2*)bias)[lane];
  float2 wv = ((const float2*)Wout)[lane];
  float hx = fmaxf(accx + b.x, 0.f);
  float hy = fmaxf(accy + b.y, 0.f);
  float p = hx*wv.x + hy*wv.y;
  #pragma unroll
  for(int off=32; off; off>>=1) p += __shfl_down(p, off);
  if(lane==0) z[wid] = p;
}

// ---------------- final: out[r] = softplus(sum val*z[col] + bout) ----------------
__global__ void k_spmm1_softplus(const int* __restrict__ row_ptr,
                                 const int2* __restrict__ pairs,
                                 const float* __restrict__ z,
                                 const float* __restrict__ bout,
                                 float* __restrict__ out, int n){
  int r = blockIdx.x*256 + threadIdx.x;
  if(r >= n) return;
  int s = row_ptr[r], e = row_ptr[r+1];
  float a0=0.f, a1=0.f, a2=0.f, a3=0.f;
  int i = s;
  for(; i+4 <= e; i += 4){
    int2 p0 = pairs[i],   p1 = pairs[i+1], p2 = pairs[i+2], p3 = pairs[i+3];
    a0 = fmaf(__int_as_float(p0.y), z[p0.x], a0);
    a1 = fmaf(__int_as_float(p1.y), z[p1.x], a1);
    a2 = fmaf(__int_as_float(p2.y), z[p2.x], a2);
    a3 = fmaf(__int_as_float(p3.y), z[p3.x], a3);
  }
  for(; i < e; i++){
    int2 p = pairs[i];
    a0 = fmaf(__int_as_float(p.y), z[p.x], a0);
  }
  float x = (a0+a1)+(a2+a3) + bout[0];
  out[r] = fmaxf(x, 0.f) + log1pf(expf(-fabsf(x)));
}

extern "C" void kernel_launch(void* const* d_in, const int* in_sizes, int n_in,
                              void* d_out, int out_size, void* d_ws, size_t ws_size,
                              hipStream_t stream){
  const float* x    = (const float*)d_in[0];
  const int*   erow = (const int*)d_in[1];
  const int*   ecol = (const int*)d_in[2];
  const float* eval = (const float*)d_in[3];
  const float* W1   = (const float*)d_in[4];
  const float* b1   = (const float*)d_in[5];
  const float* W2   = (const float*)d_in[6];
  const float* b2   = (const float*)d_in[7];
  const float* Wout = (const float*)d_in[8];
  const float* bout = (const float*)d_in[9];
  float* out = (float*)d_out;

  const int N = in_sizes[0] / 128;   // 100000
  const int E = in_sizes[1];         // 1600000

  char* p = (char*)d_ws;
  auto alloc = [&](size_t bytes)->char*{
    char* r = p; p += (bytes + 255) & ~(size_t)255; return r;
  };
  int*   cnt     = (int*)  alloc((size_t)N*4);
  int*   row_ptr = (int*)  alloc((size_t)(N+1)*4);
  int*   offs    = (int*)  alloc((size_t)N*4);
  int*   scanned = (int*)  alloc((size_t)N*4);
  int*   sums    = (int*)  alloc(4096);
  int2*  pairs   = (int2*) alloc((size_t)E*8);
  u16*   ybuf    = (u16*)  alloc((size_t)N*128*2);
  u16*   hbuf    = (u16*)  alloc((size_t)N*128*2);
  float* z       = (float*)alloc((size_t)N*4);

  // CSR build
  hipMemsetAsync(cnt, 0, (size_t)N*4, stream);
  k_hist<<<(E+255)/256, 256, 0, stream>>>(erow, cnt, E);
  int ntiles = (N+1023)/1024;
  k_scan1<<<ntiles, 1024, 0, stream>>>(cnt, scanned, sums, N);
  k_scan2<<<1, 64, 0, stream>>>(sums, ntiles);
  k_scan3<<<(N+1+255)/256, 256, 0, stream>>>(scanned, sums, row_ptr, offs, N, E);
  k_scatter<<<(E+255)/256, 256, 0, stream>>>(erow, ecol, eval, offs, pairs, E);

  // layer 1: y = x@W1 (bf16) ; h = relu(A y + b1) (bf16)
  k_gemm<false><<<(N+127)/128, 256, 0, stream>>>(x, W1, ybuf, N);
  k_spmm_relu<<<(N+3)/4, 256, 0, stream>>>(row_ptr, pairs, ybuf, b1, hbuf, N);
  // layer 2: y = h@W2 (bf16) ; z = relu(A y + b2) . Wout
  k_gemm<true><<<(N+127)/128, 256, 0, stream>>>(hbuf, W2, ybuf, N);
  k_spmm_head<<<(N+3)/4, 256, 0, stream>>>(row_ptr, pairs, ybuf, b2, Wout, z, N);
  // out = softplus(A z + bout)
  k_spmm1_softplus<<<(N+255)/256, 256, 0, stream>>>(row_ptr, pairs, z, bout, out, N);
}

// Round 10
// 526.111 us; speedup vs baseline: 1.2083x; 1.0475x over previous
//
#include <hip/hip_runtime.h>
#include <math.h>

// SimpleGNN: out = softplus(A(relu(A(relu(A(x W1)+b1) W2)+b2) Wout)+bout)
// using spmm(x) @ W == spmm(x @ W) to make the last spmm D=1.
// CSR edges as packed (col,val) int2. All N x 128 intermediates stored bf16
// (fp32 accumulation). Scatter is XCD-affine: range r of rows is handled only
// by blocks with blockIdx&7==r (dispatch round-robins blocks across 8 XCDs),
// so each pairs[] line is written from a single XCD's L2 and write-merges.

typedef unsigned int u32;
typedef unsigned short u16;

__device__ inline float bf2f(u32 lo16){ return __uint_as_float(lo16 << 16); }
__device__ inline u32 f2bf(float f){            // round-to-nearest-even
  u32 t = __float_as_uint(f);
  return (t + 0x7FFFu + ((t >> 16) & 1u)) >> 16;
}

// ---------------- CSR build ----------------
__global__ void k_hist(const int* __restrict__ row, int* __restrict__ cnt, int E){
  int e = blockIdx.x*256 + threadIdx.x;
  if(e < E) atomicAdd(&cnt[__builtin_nontemporal_load(&row[e])], 1);
}

__global__ void k_scan1(const int* __restrict__ cnt, int* __restrict__ scanned,
                        int* __restrict__ sums, int n){
  __shared__ int tmp[1024];
  int i = blockIdx.x*1024 + threadIdx.x;
  int v = (i<n)? cnt[i] : 0;
  tmp[threadIdx.x] = v;
  __syncthreads();
  for(int off=1; off<1024; off<<=1){
    int t = (threadIdx.x>=off)? tmp[threadIdx.x-off] : 0;
    __syncthreads();
    tmp[threadIdx.x] += t;
    __syncthreads();
  }
  if(i<n) scanned[i] = tmp[threadIdx.x] - v;
  if(threadIdx.x==1023) sums[blockIdx.x] = tmp[1023];
}

__global__ void k_scan2(int* sums, int ntiles){
  if(threadIdx.x==0 && blockIdx.x==0){
    int acc=0;
    for(int i=0;i<ntiles;i++){ int v=sums[i]; sums[i]=acc; acc+=v; }
  }
}

__global__ void k_scan3(const int* __restrict__ scanned, const int* __restrict__ sums,
                        int* __restrict__ row_ptr, int* __restrict__ offs, int n, int E){
  int i = blockIdx.x*256 + threadIdx.x;
  if(i<n){ int ex = scanned[i] + sums[i>>10]; row_ptr[i]=ex; offs[i]=ex; }
  else if(i==n){ row_ptr[n]=E; }
}

// XCD-affine scatter: blocks with blockIdx&7==r handle rows [r*rpr,(r+1)*rpr).
// Each block scans the whole edge stream (nt loads), filters its range, and
// writes pairs within a 1.6 MB window that stays resident in its XCD's L2.
__global__ __launch_bounds__(256) void k_scatter(const int* __restrict__ row,
                          const int* __restrict__ col,
                          const float* __restrict__ val, int* __restrict__ offs,
                          int2* __restrict__ pairs, int E, int N){
  const int r   = blockIdx.x & 7;          // range id ~ XCD (round-robin dispatch)
  const int sb  = blockIdx.x >> 3;         // sub-block within range
  const int nsb = gridDim.x >> 3;
  const int rpr = (N + 7) >> 3;
  const int lo  = r * rpr;
  const int hi  = min(lo + rpr, N);
  const int stride = nsb * 256;
  for(int e = sb*256 + threadIdx.x; e < E; e += stride){
    int rw = __builtin_nontemporal_load(&row[e]);
    if(rw >= lo && rw < hi){
      int   c = __builtin_nontemporal_load(&col[e]);
      float v = __builtin_nontemporal_load(&val[e]);
      int p = atomicAdd(&offs[rw], 1);
      pairs[p] = make_int2(c, __float_as_int(v));   // plain store -> merges in L2
    }
  }
}

// ---------------- dense GEMM: Y[n,128](bf16) = X[n,128] @ W[128,128] ----------------
// A_BF16: X is bf16 (ushort*), else fp32. Output always bf16. fp32 math.
template<bool A_BF16>
__global__ __launch_bounds__(256) void k_gemm(const void* __restrict__ Xv,
                                              const float* __restrict__ W,
                                              u16* __restrict__ Y, int n){
  __shared__ float xs_t[32][128];   // [k][row]
  __shared__ float ws[32][128];     // [k][col]
  const int t    = threadIdx.x;
  const int row0 = blockIdx.x * 128;
  const int cg   = t & 15;
  const int rg   = t >> 4;

  float acc[8][8];
  #pragma unroll
  for(int i=0;i<8;i++)
    #pragma unroll
    for(int j=0;j<8;j++) acc[i][j]=0.f;

  for(int kt=0; kt<128; kt+=32){
    {
      int r = t>>1, q = t&1;
      int gr = row0 + r;
      int kb = q*16;
      if(A_BF16){
        const u16* Xb = (const u16*)Xv;
        uint4 a = make_uint4(0,0,0,0), b = a;
        if(gr < n){
          const uint4* src = (const uint4*)(Xb + (size_t)gr*128 + kt + q*16);
          a = src[0]; b = src[1];
        }
        xs_t[kb+ 0][r]=bf2f(a.x&0xffff); xs_t[kb+ 1][r]=bf2f(a.x>>16);
        xs_t[kb+ 2][r]=bf2f(a.y&0xffff); xs_t[kb+ 3][r]=bf2f(a.y>>16);
        xs_t[kb+ 4][r]=bf2f(a.z&0xffff); xs_t[kb+ 5][r]=bf2f(a.z>>16);
        xs_t[kb+ 6][r]=bf2f(a.w&0xffff); xs_t[kb+ 7][r]=bf2f(a.w>>16);
        xs_t[kb+ 8][r]=bf2f(b.x&0xffff); xs_t[kb+ 9][r]=bf2f(b.x>>16);
        xs_t[kb+10][r]=bf2f(b.y&0xffff); xs_t[kb+11][r]=bf2f(b.y>>16);
        xs_t[kb+12][r]=bf2f(b.z&0xffff); xs_t[kb+13][r]=bf2f(b.z>>16);
        xs_t[kb+14][r]=bf2f(b.w&0xffff); xs_t[kb+15][r]=bf2f(b.w>>16);
      }else{
        const float* Xf = (const float*)Xv;
        float4 a = make_float4(0,0,0,0), b = a, c = a, d = a;
        if(gr < n){
          const float4* src = (const float4*)(Xf + (size_t)gr*128 + kt + q*16);
          a = src[0]; b = src[1]; c = src[2]; d = src[3];
        }
        xs_t[kb+ 0][r]=a.x; xs_t[kb+ 1][r]=a.y; xs_t[kb+ 2][r]=a.z; xs_t[kb+ 3][r]=a.w;
        xs_t[kb+ 4][r]=b.x; xs_t[kb+ 5][r]=b.y; xs_t[kb+ 6][r]=b.z; xs_t[kb+ 7][r]=b.w;
        xs_t[kb+ 8][r]=c.x; xs_t[kb+ 9][r]=c.y; xs_t[kb+10][r]=c.z; xs_t[kb+11][r]=c.w;
        xs_t[kb+12][r]=d.x; xs_t[kb+13][r]=d.y; xs_t[kb+14][r]=d.z; xs_t[kb+15][r]=d.w;
      }
    }
    #pragma unroll
    for(int rep=0; rep<4; rep++){
      int f  = t + rep*256;
      int kr = f >> 5;
      int cq = f & 31;
      float4 w = *(const float4*)(W + (size_t)(kt+kr)*128 + cq*4);
      *(float4*)&ws[kr][cq*4] = w;
    }
    __syncthreads();

    #pragma unroll
    for(int kk=0; kk<32; kk++){
      float4 wv0 = *(const float4*)&ws[kk][cg*8];
      float4 wv1 = *(const float4*)&ws[kk][cg*8+4];
      #pragma unroll
      for(int i=0;i<8;i++){
        float xv = xs_t[kk][rg*8+i];
        acc[i][0] = fmaf(xv, wv0.x, acc[i][0]);
        acc[i][1] = fmaf(xv, wv0.y, acc[i][1]);
        acc[i][2] = fmaf(xv, wv0.z, acc[i][2]);
        acc[i][3] = fmaf(xv, wv0.w, acc[i][3]);
        acc[i][4] = fmaf(xv, wv1.x, acc[i][4]);
        acc[i][5] = fmaf(xv, wv1.y, acc[i][5]);
        acc[i][6] = fmaf(xv, wv1.z, acc[i][6]);
        acc[i][7] = fmaf(xv, wv1.w, acc[i][7]);
      }
    }
    __syncthreads();
  }

  #pragma unroll
  for(int i=0;i<8;i++){
    int gr = row0 + rg*8 + i;
    if(gr < n){
      u32 w0 = f2bf(acc[i][0]) | (f2bf(acc[i][1])<<16);
      u32 w1 = f2bf(acc[i][2]) | (f2bf(acc[i][3])<<16);
      u32 w2 = f2bf(acc[i][4]) | (f2bf(acc[i][5])<<16);
      u32 w3 = f2bf(acc[i][6]) | (f2bf(acc[i][7])<<16);
      *(uint4*)(Y + (size_t)gr*128 + cg*8) = make_uint4(w0,w1,w2,w3);
    }
  }
}

// ---------------- SpMM (D=128 bf16) + bias + relu -> bf16 ----------------
__global__ __launch_bounds__(256) void k_spmm_relu(const int* __restrict__ row_ptr,
                                                   const int2* __restrict__ pairs,
                                                   const u16* __restrict__ y,
                                                   const float* __restrict__ bias,
                                                   u16* __restrict__ h, int n){
  int wid  = (int)((blockIdx.x*(size_t)blockDim.x + threadIdx.x) >> 6);
  int lane = threadIdx.x & 63;
  if(wid >= n) return;
  int s = row_ptr[wid], e = row_ptr[wid+1];
  float ax0=0.f, ay0=0.f, ax1=0.f, ay1=0.f, ax2=0.f, ay2=0.f, ax3=0.f, ay3=0.f;
  int i = s;
  for(; i+4 <= e; i += 4){
    int2 p0 = pairs[i], p1 = pairs[i+1], p2 = pairs[i+2], p3 = pairs[i+3];
    u32 w0 = ((const u32*)(y + (size_t)p0.x*128))[lane];
    u32 w1 = ((const u32*)(y + (size_t)p1.x*128))[lane];
    u32 w2 = ((const u32*)(y + (size_t)p2.x*128))[lane];
    u32 w3 = ((const u32*)(y + (size_t)p3.x*128))[lane];
    float v0 = __int_as_float(p0.y), v1 = __int_as_float(p1.y);
    float v2 = __int_as_float(p2.y), v3 = __int_as_float(p3.y);
    ax0 = fmaf(v0, bf2f(w0&0xffff), ax0); ay0 = fmaf(v0, bf2f(w0>>16), ay0);
    ax1 = fmaf(v1, bf2f(w1&0xffff), ax1); ay1 = fmaf(v1, bf2f(w1>>16), ay1);
    ax2 = fmaf(v2, bf2f(w2&0xffff), ax2); ay2 = fmaf(v2, bf2f(w2>>16), ay2);
    ax3 = fmaf(v3, bf2f(w3&0xffff), ax3); ay3 = fmaf(v3, bf2f(w3>>16), ay3);
  }
  for(; i < e; i++){
    int2 p = pairs[i];
    float v = __int_as_float(p.y);
    u32 w = ((const u32*)(y + (size_t)p.x*128))[lane];
    ax0 = fmaf(v, bf2f(w&0xffff), ax0); ay0 = fmaf(v, bf2f(w>>16), ay0);
  }
  float accx = (ax0+ax1)+(ax2+ax3);
  float accy = (ay0+ay1)+(ay2+ay3);
  float2 b = ((const float2*)bias)[lane];
  accx = fmaxf(accx + b.x, 0.f);
  accy = fmaxf(accy + b.y, 0.f);
  ((u32*)(h + (size_t)wid*128))[lane] = f2bf(accx) | (f2bf(accy)<<16);
}

// ---------------- SpMM(bf16) + bias + relu + head dot, fused -> z fp32 ----------------
__global__ __launch_bounds__(256) void k_spmm_head(const int* __restrict__ row_ptr,
                                                   const int2* __restrict__ pairs,
                                                   const u16* __restrict__ y,
                                                   const float* __restrict__ bias,
                                                   const float* __restrict__ Wout,
                                                   float* __restrict__ z, int n){
  int wid  = (int)((blockIdx.x*(size_t)blockDim.x + threadIdx.x) >> 6);
  int lane = threadIdx.x & 63;
  if(wid >= n) return;
  int s = row_ptr[wid], e = row_ptr[wid+1];
  float ax0=0.f, ay0=0.f, ax1=0.f, ay1=0.f, ax2=0.f, ay2=0.f, ax3=0.f, ay3=0.f;
  int i = s;
  for(; i+4 <= e; i += 4){
    int2 p0 = pairs[i], p1 = pairs[i+1], p2 = pairs[i+2], p3 = pairs[i+3];
    u32 w0 = ((const u32*)(y + (size_t)p0.x*128))[lane];
    u32 w1 = ((const u32*)(y + (size_t)p1.x*128))[lane];
    u32 w2 = ((const u32*)(y + (size_t)p2.x*128))[lane];
    u32 w3 = ((const u32*)(y + (size_t)p3.x*128))[lane];
    float v0 = __int_as_float(p0.y), v1 = __int_as_float(p1.y);
    float v2 = __int_as_float(p2.y), v3 = __int_as_float(p3.y);
    ax0 = fmaf(v0, bf2f(w0&0xffff), ax0); ay0 = fmaf(v0, bf2f(w0>>16), ay0);
    ax1 = fmaf(v1, bf2f(w1&0xffff), ax1); ay1 = fmaf(v1, bf2f(w1>>16), ay1);
    ax2 = fmaf(v2, bf2f(w2&0xffff), ax2); ay2 = fmaf(v2, bf2f(w2>>16), ay2);
    ax3 = fmaf(v3, bf2f(w3&0xffff), ax3); ay3 = fmaf(v3, bf2f(w3>>16), ay3);
  }
  for(; i < e; i++){
    int2 p = pairs[i];
    float v = __int_as_float(p.y);
    u32 w = ((const u32*)(y + (size_t)p.x*128))[lane];
    ax0 = fmaf(v, bf2f(w&0xffff), ax0); ay0 = fmaf(v, bf2f(w>>16), ay0);
  }
  float accx = (ax0+ax1)+(ax2+ax3);
  float accy = (ay0+ay1)+(ay2+ay3);
  float2 b  = ((const float2*)bias)[lane];
  float2 wv = ((const float2*)Wout)[lane];
  float hx = fmaxf(accx + b.x, 0.f);
  float hy = fmaxf(accy + b.y, 0.f);
  float p = hx*wv.x + hy*wv.y;
  #pragma unroll
  for(int off=32; off; off>>=1) p += __shfl_down(p, off);
  if(lane==0) z[wid] = p;
}

// ---------------- final: out[r] = softplus(sum val*z[col] + bout) ----------------
__global__ void k_spmm1_softplus(const int* __restrict__ row_ptr,
                                 const int2* __restrict__ pairs,
                                 const float* __restrict__ z,
                                 const float* __restrict__ bout,
                                 float* __restrict__ out, int n){
  int r = blockIdx.x*256 + threadIdx.x;
  if(r >= n) return;
  int s = row_ptr[r], e = row_ptr[r+1];
  float a0=0.f, a1=0.f, a2=0.f, a3=0.f;
  int i = s;
  for(; i+4 <= e; i += 4){
    int2 p0 = pairs[i],   p1 = pairs[i+1], p2 = pairs[i+2], p3 = pairs[i+3];
    a0 = fmaf(__int_as_float(p0.y), z[p0.x], a0);
    a1 = fmaf(__int_as_float(p1.y), z[p1.x], a1);
    a2 = fmaf(__int_as_float(p2.y), z[p2.x], a2);
    a3 = fmaf(__int_as_float(p3.y), z[p3.x], a3);
  }
  for(; i < e; i++){
    int2 p = pairs[i];
    a0 = fmaf(__int_as_float(p.y), z[p.x], a0);
  }
  float x = (a0+a1)+(a2+a3) + bout[0];
  out[r] = fmaxf(x, 0.f) + log1pf(expf(-fabsf(x)));
}

extern "C" void kernel_launch(void* const* d_in, const int* in_sizes, int n_in,
                              void* d_out, int out_size, void* d_ws, size_t ws_size,
                              hipStream_t stream){
  const float* x    = (const float*)d_in[0];
  const int*   erow = (const int*)d_in[1];
  const int*   ecol = (const int*)d_in[2];
  const float* eval = (const float*)d_in[3];
  const float* W1   = (const float*)d_in[4];
  const float* b1   = (const float*)d_in[5];
  const float* W2   = (const float*)d_in[6];
  const float* b2   = (const float*)d_in[7];
  const float* Wout = (const float*)d_in[8];
  const float* bout = (const float*)d_in[9];
  float* out = (float*)d_out;

  const int N = in_sizes[0] / 128;   // 100000
  const int E = in_sizes[1];         // 1600000

  char* p = (char*)d_ws;
  auto alloc = [&](size_t bytes)->char*{
    char* r = p; p += (bytes + 255) & ~(size_t)255; return r;
  };
  int*   cnt     = (int*)  alloc((size_t)N*4);
  int*   row_ptr = (int*)  alloc((size_t)(N+1)*4);
  int*   offs    = (int*)  alloc((size_t)N*4);
  int*   scanned = (int*)  alloc((size_t)N*4);
  int*   sums    = (int*)  alloc(4096);
  int2*  pairs   = (int2*) alloc((size_t)E*8);
  u16*   ybuf    = (u16*)  alloc((size_t)N*128*2);
  u16*   hbuf    = (u16*)  alloc((size_t)N*128*2);
  float* z       = (float*)alloc((size_t)N*4);

  // CSR build
  hipMemsetAsync(cnt, 0, (size_t)N*4, stream);
  k_hist<<<(E+255)/256, 256, 0, stream>>>(erow, cnt, E);
  int ntiles = (N+1023)/1024;
  k_scan1<<<ntiles, 1024, 0, stream>>>(cnt, scanned, sums, N);
  k_scan2<<<1, 64, 0, stream>>>(sums, ntiles);
  k_scan3<<<(N+1+255)/256, 256, 0, stream>>>(scanned, sums, row_ptr, offs, N, E);
  k_scatter<<<1024, 256, 0, stream>>>(erow, ecol, eval, offs, pairs, E, N);

  // layer 1: y = x@W1 (bf16) ; h = relu(A y + b1) (bf16)
  k_gemm<false><<<(N+127)/128, 256, 0, stream>>>(x, W1, ybuf, N);
  k_spmm_relu<<<(N+3)/4, 256, 0, stream>>>(row_ptr, pairs, ybuf, b1, hbuf, N);
  // layer 2: y = h@W2 (bf16) ; z = relu(A y + b2) . Wout
  k_gemm<true><<<(N+127)/128, 256, 0, stream>>>(hbuf, W2, ybuf, N);
  k_spmm_head<<<(N+3)/4, 256, 0, stream>>>(row_ptr, pairs, ybuf, b2, Wout, z, N);
  // out = softplus(A z + bout)
  k_spmm1_softplus<<<(N+255)/256, 256, 0, stream>>>(row_ptr, pairs, z, bout, out, N);
}

// Round 11
// 499.408 us; speedup vs baseline: 1.2729x; 1.0535x over previous
//
#include <hip/hip_runtime.h>
#include <math.h>

// SimpleGNN: out = softplus(A(relu(A(relu(A(x W1)+b1) W2)+b2) Wout)+bout)
// using spmm(x) @ W == spmm(x @ W) to make the last spmm D=1.
// CSR edges as packed (col,val) int2; XCD-affine scatter (blockIdx&7 = row range).
// All N x 128 intermediates bf16 (fp32 accumulation).
// GEMMs use v_mfma_f32_16x16x32_bf16 with 128x128 block tile, 64KB LDS,
// XOR-chunk swizzle for conflict-free bf16x8 fragment reads.

typedef unsigned int u32;
typedef unsigned short u16;
typedef __attribute__((ext_vector_type(8))) short bf16x8;
typedef __attribute__((ext_vector_type(4))) float f32x4;

__device__ inline float bf2f(u32 lo16){ return __uint_as_float(lo16 << 16); }
__device__ inline u32 f2bf(float f){            // round-to-nearest-even
  u32 t = __float_as_uint(f);
  return (t + 0x7FFFu + ((t >> 16) & 1u)) >> 16;
}

// ---------------- CSR build ----------------
__global__ void k_hist(const int* __restrict__ row, int* __restrict__ cnt, int E){
  int e = blockIdx.x*256 + threadIdx.x;
  if(e < E) atomicAdd(&cnt[row[e]], 1);     // plain load: row stays L3-resident
}

__global__ void k_scan1(const int* __restrict__ cnt, int* __restrict__ scanned,
                        int* __restrict__ sums, int n){
  __shared__ int tmp[1024];
  int i = blockIdx.x*1024 + threadIdx.x;
  int v = (i<n)? cnt[i] : 0;
  tmp[threadIdx.x] = v;
  __syncthreads();
  for(int off=1; off<1024; off<<=1){
    int t = (threadIdx.x>=off)? tmp[threadIdx.x-off] : 0;
    __syncthreads();
    tmp[threadIdx.x] += t;
    __syncthreads();
  }
  if(i<n) scanned[i] = tmp[threadIdx.x] - v;
  if(threadIdx.x==1023) sums[blockIdx.x] = tmp[1023];
}

__global__ void k_scan2(int* sums, int ntiles){
  if(threadIdx.x==0 && blockIdx.x==0){
    int acc=0;
    for(int i=0;i<ntiles;i++){ int v=sums[i]; sums[i]=acc; acc+=v; }
  }
}

__global__ void k_scan3(const int* __restrict__ scanned, const int* __restrict__ sums,
                        int* __restrict__ row_ptr, int* __restrict__ offs, int n, int E){
  int i = blockIdx.x*256 + threadIdx.x;
  if(i<n){ int ex = scanned[i] + sums[i>>10]; row_ptr[i]=ex; offs[i]=ex; }
  else if(i==n){ row_ptr[n]=E; }
}

// XCD-affine scatter: blocks with blockIdx&7==r handle rows [r*rpr,(r+1)*rpr).
// row[] read with plain loads (8 passes -> L3 hits); col/val nt (single use).
__global__ __launch_bounds__(256) void k_scatter(const int* __restrict__ row,
                          const int* __restrict__ col,
                          const float* __restrict__ val, int* __restrict__ offs,
                          int2* __restrict__ pairs, int E, int N){
  const int r   = blockIdx.x & 7;
  const int sb  = blockIdx.x >> 3;
  const int nsb = gridDim.x >> 3;
  const int rpr = (N + 7) >> 3;
  const int lo  = r * rpr;
  const int hi  = min(lo + rpr, N);
  const int stride = nsb * 256;
  for(int e = sb*256 + threadIdx.x; e < E; e += stride){
    int rw = row[e];
    if(rw >= lo && rw < hi){
      int   c = __builtin_nontemporal_load(&col[e]);
      float v = __builtin_nontemporal_load(&val[e]);
      int p = atomicAdd(&offs[rw], 1);
      pairs[p] = make_int2(c, __float_as_int(v));
    }
  }
}

// ---------------- W pre-transpose + cvt: Wt[n][k] bf16 = W[k][n] fp32 ----------------
__global__ void k_cvtW(const float* __restrict__ W, u16* __restrict__ Wt){
  int t = blockIdx.x*256 + threadIdx.x;     // 16384 elements
  int nn = t >> 7, k = t & 127;
  Wt[nn*128 + k] = (u16)f2bf(W[k*128 + nn]);
}

// ---------------- MFMA GEMM: Y[n,128](bf16) = X[n,128] @ W[128,128] ----------------
// A_BF16: X bf16 (u16*) else fp32 (converted during staging). Wt is [n][k] bf16.
// 128x128 tile, 4 waves; wave w owns rows [w*32,w*32+32). LDS chunk-swizzle:
// 16B chunk index c within a 256B row is stored at c ^ (rowidx & 15).
template<bool A_BF16>
__global__ __launch_bounds__(256) void k_gemm(const void* __restrict__ Xv,
                                              const u16* __restrict__ Wt,
                                              u16* __restrict__ Y, int n){
  __shared__ u16 As[128*128];
  __shared__ u16 Bs[128*128];
  const int t = threadIdx.x;
  const int row0 = blockIdx.x * 128;

  // stage B: rows of Wt (n-index r), 8 uint4 per thread
  {
    int r = t>>1, q = t&1;
    const uint4* src = (const uint4*)(Wt + r*128 + q*64);
    #pragma unroll
    for(int i=0;i<8;i++){
      uint4 v = src[i];
      int c = q*8 + i;
      *(uint4*)&Bs[r*128 + ((c ^ (r&15))<<3)] = v;
    }
  }
  // stage A
  {
    int r = t>>1, q = t&1;
    int gr = row0 + r;
    if(A_BF16){
      const uint4* src = (const uint4*)((const u16*)Xv + (size_t)gr*128 + q*64);
      uint4 z = make_uint4(0,0,0,0);
      #pragma unroll
      for(int i=0;i<8;i++){
        uint4 v = (gr<n)? src[i] : z;
        int c = q*8 + i;
        *(uint4*)&As[r*128 + ((c ^ (r&15))<<3)] = v;
      }
    }else{
      const float4* src = (const float4*)((const float*)Xv + (size_t)gr*128 + q*64);
      float4 z4 = make_float4(0,0,0,0);
      #pragma unroll
      for(int i=0;i<8;i++){
        float4 a = (gr<n)? src[2*i]   : z4;
        float4 b = (gr<n)? src[2*i+1] : z4;
        uint4 v = make_uint4(f2bf(a.x)|(f2bf(a.y)<<16), f2bf(a.z)|(f2bf(a.w)<<16),
                             f2bf(b.x)|(f2bf(b.y)<<16), f2bf(b.z)|(f2bf(b.w)<<16));
        int c = q*8 + i;
        *(uint4*)&As[r*128 + ((c ^ (r&15))<<3)] = v;
      }
    }
  }
  __syncthreads();

  const int w  = t>>6, l = t&63;
  const int lr = l & 15;          // row/col-in-frag
  const int kg = l >> 4;          // k-group (8 bf16 each)
  f32x4 acc[2][8];
  #pragma unroll
  for(int mi=0;mi<2;mi++)
    #pragma unroll
    for(int ni=0;ni<8;ni++) acc[mi][ni] = (f32x4){0.f,0.f,0.f,0.f};

  #pragma unroll
  for(int kt=0; kt<4; kt++){
    int c = kt*4 + kg;
    bf16x8 a0 = *(const bf16x8*)&As[(w*32 + lr)*128      + ((c ^ lr)<<3)];
    bf16x8 a1 = *(const bf16x8*)&As[(w*32 + 16 + lr)*128 + ((c ^ lr)<<3)];
    #pragma unroll
    for(int ni=0; ni<8; ni++){
      bf16x8 b = *(const bf16x8*)&Bs[(ni*16 + lr)*128 + ((c ^ lr)<<3)];
      acc[0][ni] = __builtin_amdgcn_mfma_f32_16x16x32_bf16(a0, b, acc[0][ni], 0,0,0);
      acc[1][ni] = __builtin_amdgcn_mfma_f32_16x16x32_bf16(a1, b, acc[1][ni], 0,0,0);
    }
  }

  // C/D layout (m89): col = lane&15, row = (lane>>4)*4 + reg
  #pragma unroll
  for(int mi=0;mi<2;mi++){
    #pragma unroll
    for(int r=0;r<4;r++){
      int grow = row0 + w*32 + mi*16 + kg*4 + r;
      if(grow < n){
        #pragma unroll
        for(int ni=0;ni<8;ni++){
          Y[(size_t)grow*128 + ni*16 + lr] = (u16)f2bf(acc[mi][ni][r]);
        }
      }
    }
  }
}

// ---------------- SpMM (D=128 bf16) + bias + relu -> bf16 ----------------
__global__ __launch_bounds__(256) void k_spmm_relu(const int* __restrict__ row_ptr,
                                                   const int2* __restrict__ pairs,
                                                   const u16* __restrict__ y,
                                                   const float* __restrict__ bias,
                                                   u16* __restrict__ h, int n){
  int wid  = (int)((blockIdx.x*(size_t)blockDim.x + threadIdx.x) >> 6);
  int lane = threadIdx.x & 63;
  if(wid >= n) return;
  int s = row_ptr[wid], e = row_ptr[wid+1];
  float ax0=0.f, ay0=0.f, ax1=0.f, ay1=0.f, ax2=0.f, ay2=0.f, ax3=0.f, ay3=0.f;
  int i = s;
  for(; i+4 <= e; i += 4){
    int2 p0 = pairs[i], p1 = pairs[i+1], p2 = pairs[i+2], p3 = pairs[i+3];
    u32 w0 = ((const u32*)(y + (size_t)p0.x*128))[lane];
    u32 w1 = ((const u32*)(y + (size_t)p1.x*128))[lane];
    u32 w2 = ((const u32*)(y + (size_t)p2.x*128))[lane];
    u32 w3 = ((const u32*)(y + (size_t)p3.x*128))[lane];
    float v0 = __int_as_float(p0.y), v1 = __int_as_float(p1.y);
    float v2 = __int_as_float(p2.y), v3 = __int_as_float(p3.y);
    ax0 = fmaf(v0, bf2f(w0&0xffff), ax0); ay0 = fmaf(v0, bf2f(w0>>16), ay0);
    ax1 = fmaf(v1, bf2f(w1&0xffff), ax1); ay1 = fmaf(v1, bf2f(w1>>16), ay1);
    ax2 = fmaf(v2, bf2f(w2&0xffff), ax2); ay2 = fmaf(v2, bf2f(w2>>16), ay2);
    ax3 = fmaf(v3, bf2f(w3&0xffff), ax3); ay3 = fmaf(v3, bf2f(w3>>16), ay3);
  }
  for(; i < e; i++){
    int2 p = pairs[i];
    float v = __int_as_float(p.y);
    u32 w = ((const u32*)(y + (size_t)p.x*128))[lane];
    ax0 = fmaf(v, bf2f(w&0xffff), ax0); ay0 = fmaf(v, bf2f(w>>16), ay0);
  }
  float accx = (ax0+ax1)+(ax2+ax3);
  float accy = (ay0+ay1)+(ay2+ay3);
  float2 b = ((const float2*)bias)[lane];
  accx = fmaxf(accx + b.x, 0.f);
  accy = fmaxf(accy + b.y, 0.f);
  ((u32*)(h + (size_t)wid*128))[lane] = f2bf(accx) | (f2bf(accy)<<16);
}

// ---------------- SpMM(bf16) + bias + relu + head dot, fused -> z fp32 ----------------
__global__ __launch_bounds__(256) void k_spmm_head(const int* __restrict__ row_ptr,
                                                   const int2* __restrict__ pairs,
                                                   const u16* __restrict__ y,
                                                   const float* __restrict__ bias,
                                                   const float* __restrict__ Wout,
                                                   float* __restrict__ z, int n){
  int wid  = (int)((blockIdx.x*(size_t)blockDim.x + threadIdx.x) >> 6);
  int lane = threadIdx.x & 63;
  if(wid >= n) return;
  int s = row_ptr[wid], e = row_ptr[wid+1];
  float ax0=0.f, ay0=0.f, ax1=0.f, ay1=0.f, ax2=0.f, ay2=0.f, ax3=0.f, ay3=0.f;
  int i = s;
  for(; i+4 <= e; i += 4){
    int2 p0 = pairs[i], p1 = pairs[i+1], p2 = pairs[i+2], p3 = pairs[i+3];
    u32 w0 = ((const u32*)(y + (size_t)p0.x*128))[lane];
    u32 w1 = ((const u32*)(y + (size_t)p1.x*128))[lane];
    u32 w2 = ((const u32*)(y + (size_t)p2.x*128))[lane];
    u32 w3 = ((const u32*)(y + (size_t)p3.x*128))[lane];
    float v0 = __int_as_float(p0.y), v1 = __int_as_float(p1.y);
    float v2 = __int_as_float(p2.y), v3 = __int_as_float(p3.y);
    ax0 = fmaf(v0, bf2f(w0&0xffff), ax0); ay0 = fmaf(v0, bf2f(w0>>16), ay0);
    ax1 = fmaf(v1, bf2f(w1&0xffff), ax1); ay1 = fmaf(v1, bf2f(w1>>16), ay1);
    ax2 = fmaf(v2, bf2f(w2&0xffff), ax2); ay2 = fmaf(v2, bf2f(w2>>16), ay2);
    ax3 = fmaf(v3, bf2f(w3&0xffff), ax3); ay3 = fmaf(v3, bf2f(w3>>16), ay3);
  }
  for(; i < e; i++){
    int2 p = pairs[i];
    float v = __int_as_float(p.y);
    u32 w = ((const u32*)(y + (size_t)p.x*128))[lane];
    ax0 = fmaf(v, bf2f(w&0xffff), ax0); ay0 = fmaf(v, bf2f(w>>16), ay0);
  }
  float accx = (ax0+ax1)+(ax2+ax3);
  float accy = (ay0+ay1)+(ay2+ay3);
  float2 b  = ((const float2*)bias)[lane];
  float2 wv = ((const float2*)Wout)[lane];
  float hx = fmaxf(accx + b.x, 0.f);
  float hy = fmaxf(accy + b.y, 0.f);
  float p = hx*wv.x + hy*wv.y;
  #pragma unroll
  for(int off=32; off; off>>=1) p += __shfl_down(p, off);
  if(lane==0) z[wid] = p;
}

// ---------------- final: out[r] = softplus(sum val*z[col] + bout) ----------------
__global__ void k_spmm1_softplus(const int* __restrict__ row_ptr,
                                 const int2* __restrict__ pairs,
                                 const float* __restrict__ z,
                                 const float* __restrict__ bout,
                                 float* __restrict__ out, int n){
  int r = blockIdx.x*256 + threadIdx.x;
  if(r >= n) return;
  int s = row_ptr[r], e = row_ptr[r+1];
  float a0=0.f, a1=0.f, a2=0.f, a3=0.f;
  int i = s;
  for(; i+4 <= e; i += 4){
    int2 p0 = pairs[i],   p1 = pairs[i+1], p2 = pairs[i+2], p3 = pairs[i+3];
    a0 = fmaf(__int_as_float(p0.y), z[p0.x], a0);
    a1 = fmaf(__int_as_float(p1.y), z[p1.x], a1);
    a2 = fmaf(__int_as_float(p2.y), z[p2.x], a2);
    a3 = fmaf(__int_as_float(p3.y), z[p3.x], a3);
  }
  for(; i < e; i++){
    int2 p = pairs[i];
    a0 = fmaf(__int_as_float(p.y), z[p.x], a0);
  }
  float x = (a0+a1)+(a2+a3) + bout[0];
  out[r] = fmaxf(x, 0.f) + log1pf(expf(-fabsf(x)));
}

extern "C" void kernel_launch(void* const* d_in, const int* in_sizes, int n_in,
                              void* d_out, int out_size, void* d_ws, size_t ws_size,
                              hipStream_t stream){
  const float* x    = (const float*)d_in[0];
  const int*   erow = (const int*)d_in[1];
  const int*   ecol = (const int*)d_in[2];
  const float* eval = (const float*)d_in[3];
  const float* W1   = (const float*)d_in[4];
  const float* b1   = (const float*)d_in[5];
  const float* W2   = (const float*)d_in[6];
  const float* b2   = (const float*)d_in[7];
  const float* Wout = (const float*)d_in[8];
  const float* bout = (const float*)d_in[9];
  float* out = (float*)d_out;

  const int N = in_sizes[0] / 128;   // 100000
  const int E = in_sizes[1];         // 1600000

  char* p = (char*)d_ws;
  auto alloc = [&](size_t bytes)->char*{
    char* r = p; p += (bytes + 255) & ~(size_t)255; return r;
  };
  int*   cnt     = (int*)  alloc((size_t)N*4);
  int*   row_ptr = (int*)  alloc((size_t)(N+1)*4);
  int*   offs    = (int*)  alloc((size_t)N*4);
  int*   scanned = (int*)  alloc((size_t)N*4);
  int*   sums    = (int*)  alloc(4096);
  int2*  pairs   = (int2*) alloc((size_t)E*8);
  u16*   ybuf    = (u16*)  alloc((size_t)N*128*2);
  u16*   hbuf    = (u16*)  alloc((size_t)N*128*2);
  float* z       = (float*)alloc((size_t)N*4);
  u16*   Wt1     = (u16*)  alloc(128*128*2);
  u16*   Wt2     = (u16*)  alloc(128*128*2);

  // CSR build
  hipMemsetAsync(cnt, 0, (size_t)N*4, stream);
  k_hist<<<(E+255)/256, 256, 0, stream>>>(erow, cnt, E);
  int ntiles = (N+1023)/1024;
  k_scan1<<<ntiles, 1024, 0, stream>>>(cnt, scanned, sums, N);
  k_scan2<<<1, 64, 0, stream>>>(sums, ntiles);
  k_scan3<<<(N+1+255)/256, 256, 0, stream>>>(scanned, sums, row_ptr, offs, N, E);
  k_scatter<<<1024, 256, 0, stream>>>(erow, ecol, eval, offs, pairs, E, N);

  // W pre-transpose/convert
  k_cvtW<<<64, 256, 0, stream>>>(W1, Wt1);
  k_cvtW<<<64, 256, 0, stream>>>(W2, Wt2);

  // layer 1: y = x@W1 (bf16 MFMA) ; h = relu(A y + b1) (bf16)
  k_gemm<false><<<(N+127)/128, 256, 0, stream>>>(x, Wt1, ybuf, N);
  k_spmm_relu<<<(N+3)/4, 256, 0, stream>>>(row_ptr, pairs, ybuf, b1, hbuf, N);
  // layer 2: y = h@W2 (bf16 MFMA) ; z = relu(A y + b2) . Wout
  k_gemm<true><<<(N+127)/128, 256, 0, stream>>>(hbuf, Wt2, ybuf, N);
  k_spmm_head<<<(N+3)/4, 256, 0, stream>>>(row_ptr, pairs, ybuf, b2, Wout, z, N);
  // out = softplus(A z + bout)
  k_spmm1_softplus<<<(N+255)/256, 256, 0, stream>>>(row_ptr, pairs, z, bout, out, N);
}